// Round 13
// baseline (157.331 us; speedup 1.0000x reference)
//
#include <hip/hip_runtime.h>

#define NTYPES 6
#define HID 128
#define E_TILE 64
#define TPB 4
#define TNBITS 19
#define TNMASK ((1 << TNBITS) - 1)
#define DEG1F 0x40000000
#define OFFM  0x3FFFFFFF

typedef short short8 __attribute__((ext_vector_type(8)));
typedef float f32x4 __attribute__((ext_vector_type(4)));

static __device__ __forceinline__ ushort f2bf(float f) {
    union { float f; unsigned u; } v; v.f = f;
    unsigned r = v.u + 0x7FFFu + ((v.u >> 16) & 1u);   // RNE
    return (ushort)(r >> 16);
}

// ws ints: hdr[32] | ncnt[N] | noff[N+1] | bsum[256]
// then 256B-aligned: sortedT2 int2[6*CAP] | Wt bf16[6][128][256] | Sb bf16[N][128] | msgs bf16[E][128]

// fused: zero(hdr+ncnt) || state f32->bf16 || W transpose/convert (block-range split)
__global__ void k_prep(int4* __restrict__ zp, int n4,
                       const float* __restrict__ Sf, ushort* __restrict__ Sb, int total,
                       const float* __restrict__ W, ushort* __restrict__ Wt,
                       int zb, int sb) {
    int b = blockIdx.x;
    if (b < zb) {
        int i = b * 256 + threadIdx.x;
        if (i < n4) zp[i] = make_int4(0, 0, 0, 0);
    } else if (b < zb + sb) {
        int g = ((b - zb) * 256 + threadIdx.x) * 8;
        if (g < total) {
            float4 a = *(const float4*)(Sf + g);
            float4 c = *(const float4*)(Sf + g + 4);
            ushort t[8] = { f2bf(a.x), f2bf(a.y), f2bf(a.z), f2bf(a.w),
                            f2bf(c.x), f2bf(c.y), f2bf(c.z), f2bf(c.w) };
            *(short8*)(Sb + g) = *(short8*)t;
        }
    } else {
        int t = (b - zb - sb) * 256 + threadIdx.x;
        int n  = t & 127;
        int k8 = (t >> 7) & 31;
        int ty = t >> 12;
        if (ty >= NTYPES) return;
        const float* wp = W + ((size_t)ty * 256 + (size_t)k8 * 8) * HID + n;
        ushort tmp[8];
        #pragma unroll
        for (int j = 0; j < 8; ++j) tmp[j] = f2bf(wp[(size_t)j * HID]);
        *(short8*)(Wt + ((size_t)ty * HID + n) * 256 + k8 * 8) = *(short8*)tmp;
    }
}

// single-pass type binning; packs {src, tgt | rank<<19} into per-type regions
template <int RANK>
__global__ void k_bin(const int* __restrict__ etype, const int* __restrict__ src,
                      const int* __restrict__ tgt, int E, int CAP,
                      int* __restrict__ hdr, int* __restrict__ ncnt,
                      int2* __restrict__ sortedT2) {
    __shared__ int lcnt[NTYPES];
    __shared__ int lbase[NTYPES];
    if (threadIdx.x < NTYPES) lcnt[threadIdx.x] = 0;
    __syncthreads();
    int i = blockIdx.x * 256 + threadIdx.x;
    bool valid = (i < E);
    int sn = 0, pk = 0, t = 0, lrk = 0;
    if (valid) {
        t  = etype[i] - 1;
        int tn = tgt[i];
        sn = src[i];
        int a = 0;
        if (RANK) a = atomicAdd(&ncnt[tn], 1);
        pk  = tn | (a << TNBITS);
        lrk = atomicAdd(&lcnt[t], 1);
    }
    __syncthreads();
    if (threadIdx.x < NTYPES) {
        int c = lcnt[threadIdx.x];
        lbase[threadIdx.x] = c ? atomicAdd(&hdr[16 + threadIdx.x], c) : 0;
    }
    __syncthreads();
    if (valid) {
        int pos = lbase[t] + lrk;
        if (pos < CAP) sortedT2[(size_t)t * CAP + pos] = make_int2(sn, pk);
    }
}

// per-1024-chunk exclusive scan; bsum[b] = chunk total; deg-1 flag in bit 30
__global__ void k_scan1(const int* __restrict__ ncnt, int* __restrict__ noff,
                        int* __restrict__ bsum, int N) {
    __shared__ int s[256];
    const int b = blockIdx.x, t = threadIdx.x;
    const int base = b * 1024 + t * 4;
    int v[4];
    #pragma unroll
    for (int i = 0; i < 4; ++i) v[i] = (base + i < N) ? ncnt[base + i] : 0;
    int tsum = v[0] + v[1] + v[2] + v[3];
    s[t] = tsum;
    __syncthreads();
    for (int off = 1; off < 256; off <<= 1) {
        int x = (t >= off) ? s[t - off] : 0;
        __syncthreads();
        s[t] += x;
        __syncthreads();
    }
    if (t == 255) bsum[b] = s[255];
    int run = s[t] - tsum;
    #pragma unroll
    for (int i = 0; i < 4; ++i)
        if (base + i < N) {
            noff[base + i] = run | ((v[i] == 1) ? DEG1F : 0);
            run += v[i];
        }
}

__global__ void k_scan2(int* __restrict__ bsum, int nb) {
    __shared__ int s[256];
    const int t = threadIdx.x;
    int v = (t < nb) ? bsum[t] : 0;
    s[t] = v;
    __syncthreads();
    for (int off = 1; off < 256; off <<= 1) {
        int x = (t >= off) ? s[t - off] : 0;
        __syncthreads();
        s[t] += x;
        __syncthreads();
    }
    if (t < nb) bsum[t] = s[t] - v;   // exclusive
}

// ---------------- GEMM ----------------
// Block = TPB 64-edge tiles of ONE type. B fragments per-K-step from L2.
// T14 pipeline (MODE 2): staged rows live in 8xshort8 regs; tile t+1's gather
// issues right after tile t's staging barrier and completes under MFMA+epilogue.
// deg-1 (noff bit30) -> direct f32 out write. MODE 0: f32 gather + atomics.
template <int MODE>
__launch_bounds__(256, 4)
__global__ void k_gemm(const ushort* __restrict__ Sb, const float* __restrict__ Sf,
                       const ushort* __restrict__ Wt, const int* __restrict__ hdr,
                       const int2* __restrict__ sortedT2, int CAP,
                       const int* __restrict__ noff, const int* __restrict__ bsum,
                       ushort* __restrict__ msgs, float* __restrict__ out) {
    __shared__ __align__(16) ushort Xs[E_TILE][264];   // 33792 B
    __shared__ int sN[TPB][E_TILE];
    __shared__ int tN[TPB][E_TILE];
    __shared__ int dstR[TPB][E_TILE];

    // map blockIdx -> (type, tile-group)
    int g = blockIdx.x;
    int ty, t0 = 0, ntl = 0, cnt_t = 0;
    for (ty = 0; ty < NTYPES; ++ty) {
        int c = hdr[16 + ty];
        if (c > CAP) c = CAP;
        int nt = (c + E_TILE - 1) >> 6;
        int ng = (nt + TPB - 1) / TPB;
        if (g < ng) {
            t0 = g * TPB;
            ntl = nt - t0; if (ntl > TPB) ntl = TPB;
            cnt_t = c;
            break;
        }
        g -= ng;
    }
    if (ty == NTYPES) return;

    const int tid = threadIdx.x;
    const int w  = tid >> 6;
    const int l  = tid & 63;
    const int lr = l & 15;
    const int lg = l >> 4;

    // index prefetch: wave tt covers tile tt (coalesced int2 loads)
    {
        const int tt = tid >> 6, s = l;
        if (tt < ntl) {
            int gp = (t0 + tt) * E_TILE + s;
            int sn = 0, tn = 0, dr = 0;
            if (gp < cnt_t) {
                int2 v = sortedT2[(size_t)ty * CAP + gp];
                sn = v.x;
                tn = v.y & TNMASK;
                if (MODE == 2) {
                    int a = ((unsigned)v.y) >> TNBITS;
                    int nf_ = noff[tn];
                    dr = (nf_ & DEG1F) ? -(tn + 1)
                                       : ((nf_ & OFFM) + bsum[tn >> 10] + a);
                }
            }
            sN[tt][s] = sn; tN[tt][s] = tn; dstR[tt][s] = dr;
        }
    }
    __syncthreads();

    // B-fragment base for this wave's 32 cols (L2-hot; offsets compile-time)
    const ushort* wb = Wt + ((size_t)ty * HID + w * 32 + lr) * 256 + 8 * lg;

    const int e_ = tid >> 2, q_ = tid & 3;   // staging: 4 threads/edge, 128 B each
    const short8 z8 = (short8){0, 0, 0, 0, 0, 0, 0, 0};
    short8 pv[8];

    // prologue: prefetch tile 0 rows into registers
    if (MODE == 2) {
        int cnt0 = cnt_t - t0 * E_TILE; if (cnt0 > E_TILE) cnt0 = E_TILE;
        if (e_ < cnt0) {
            const int node = (q_ & 2) ? tN[0][e_] : sN[0][e_];
            const ushort* rp = Sb + (size_t)node * HID + (q_ & 1) * 64;
            #pragma unroll
            for (int i = 0; i < 8; ++i) pv[i] = *(const short8*)(rp + i * 8);
        } else {
            #pragma unroll
            for (int i = 0; i < 8; ++i) pv[i] = z8;
        }
    }

    for (int tt = 0; tt < ntl; ++tt) {
        int cnt = cnt_t - (t0 + tt) * E_TILE;
        if (cnt > E_TILE) cnt = E_TILE;

        // ---- stage: regs -> Xs (MODE 2) or direct f32 gather (MODE 0) ----
        if (MODE == 2) {
            ushort* dp = &Xs[e_][q_ * 64];
            #pragma unroll
            for (int i = 0; i < 8; ++i) *(short8*)(dp + i * 8) = pv[i];
        } else {
            ushort* dp = &Xs[e_][q_ * 64];
            if (e_ < cnt) {
                const int node = (q_ & 2) ? tN[tt][e_] : sN[tt][e_];
                const float* rp = Sf + (size_t)node * HID + (q_ & 1) * 64;
                #pragma unroll
                for (int i = 0; i < 8; ++i) {
                    float4 a = *(const float4*)(rp + i * 8);
                    float4 b = *(const float4*)(rp + i * 8 + 4);
                    ushort tmp[8] = { f2bf(a.x), f2bf(a.y), f2bf(a.z), f2bf(a.w),
                                      f2bf(b.x), f2bf(b.y), f2bf(b.z), f2bf(b.w) };
                    *(short8*)(dp + i * 8) = *(short8*)tmp;
                }
            } else {
                #pragma unroll
                for (int i = 0; i < 8; ++i) *(short8*)(dp + i * 8) = z8;
            }
        }
        __syncthreads();

        // ---- T14: issue next tile's gather now; completes under MFMA+epilogue ----
        if (MODE == 2 && tt + 1 < ntl) {
            int cntn = cnt_t - (t0 + tt + 1) * E_TILE; if (cntn > E_TILE) cntn = E_TILE;
            if (e_ < cntn) {
                const int node = (q_ & 2) ? tN[tt + 1][e_] : sN[tt + 1][e_];
                const ushort* rp = Sb + (size_t)node * HID + (q_ & 1) * 64;
                #pragma unroll
                for (int i = 0; i < 8; ++i) pv[i] = *(const short8*)(rp + i * 8);
            } else {
                #pragma unroll
                for (int i = 0; i < 8; ++i) pv[i] = z8;
            }
        }

        // ---- MFMA: wave w -> 64 edges x cols [w*32, w*32+32); B per-kk from L2 ----
        f32x4 acc[4][2];
        #pragma unroll
        for (int mf = 0; mf < 4; ++mf)
            #pragma unroll
            for (int nf = 0; nf < 2; ++nf)
                acc[mf][nf] = (f32x4){0.f, 0.f, 0.f, 0.f};

        const ushort* xb = &Xs[lr][8 * lg];
        #pragma unroll
        for (int kk = 0; kk < 8; ++kk) {
            const int k0 = kk * 32;
            short8 b0 = *(const short8*)(wb + k0);
            short8 b1 = *(const short8*)(wb + 16 * 256 + k0);
            #pragma unroll
            for (int mf = 0; mf < 4; ++mf) {
                short8 a = *(const short8*)(xb + mf * 16 * 264 + k0);
                acc[mf][0] = __builtin_amdgcn_mfma_f32_16x16x32_bf16(a, b0, acc[mf][0], 0, 0, 0);
                acc[mf][1] = __builtin_amdgcn_mfma_f32_16x16x32_bf16(a, b1, acc[mf][1], 0, 0, 0);
            }
        }
        __syncthreads();   // Xs reads done before Os overlay

        float (*Os)[132] = (float (*)[132])&Xs[0][0];   // 64*132*4 = 33792 B exactly
        #pragma unroll
        for (int mf = 0; mf < 4; ++mf)
            #pragma unroll
            for (int nf = 0; nf < 2; ++nf)
                #pragma unroll
                for (int r = 0; r < 4; ++r)
                    Os[mf * 16 + lg * 4 + r][w * 32 + nf * 16 + lr] = acc[mf][nf][r];
        __syncthreads();

        if (MODE == 2) {
            const int r8e = tid >> 4, cg = tid & 15;
            #pragma unroll
            for (int rr = 0; rr < 4; ++rr) {
                int row = rr * 16 + r8e;
                if (row < cnt) {
                    int dr = dstR[tt][row];
                    float4 a = *(const float4*)&Os[row][cg * 8];
                    float4 b = *(const float4*)&Os[row][cg * 8 + 4];
                    if (dr >= 0) {
                        ushort tmp[8] = { f2bf(a.x), f2bf(a.y), f2bf(a.z), f2bf(a.w),
                                          f2bf(b.x), f2bf(b.y), f2bf(b.z), f2bf(b.w) };
                        *(short8*)(msgs + (size_t)dr * HID + cg * 8) = *(short8*)tmp;
                    } else {
                        float* op = out + (size_t)(-dr - 1) * HID + cg * 8;
                        *(float4*)op = a;
                        *(float4*)(op + 4) = b;
                    }
                }
            }
        } else {
            const int rA = tid >> 7;
            const int c  = tid & (HID - 1);
            for (int it = 0; it < E_TILE / 2; ++it) {
                int ee = it * 2 + rA;
                if (ee < cnt) atomicAdd(&out[(size_t)tN[tt][ee] * HID + c], Os[ee][c]);
            }
        }
        __syncthreads();   // Os reads done before next tile's staging
    }
}

// each 64-lane group owns one node; deg-1 rows (noff bit30) were written by gemm
__launch_bounds__(256)
__global__ void k_scatter(const ushort* __restrict__ msgs, const int* __restrict__ noff,
                          const int* __restrict__ bsum, float* __restrict__ out,
                          int N, int Etot) {
    int node = blockIdx.x * 4 + (threadIdx.x >> 6);
    if (node >= N) return;
    int raw = noff[node];
    if (raw & DEG1F) return;   // deg-1: gemm wrote f32 row directly
    int cp = threadIdx.x & 63;
    int s = (raw & OFFM) + bsum[node >> 10];
    int e = (node + 1 < N) ? ((noff[node + 1] & OFFM) + bsum[(node + 1) >> 10]) : Etot;
    float a0 = 0.f, a1 = 0.f;
    for (int r = s; r < e; ++r) {
        unsigned u = *(const unsigned*)(msgs + (size_t)r * HID + cp * 2);
        union { unsigned u; float f; } lo, hi;
        lo.u = u << 16; hi.u = u & 0xFFFF0000u;
        a0 += lo.f; a1 += hi.f;
    }
    *(float2*)(out + (size_t)node * HID + cp * 2) = make_float2(a0, a1);
}

extern "C" void kernel_launch(void* const* d_in, const int* in_sizes, int n_in,
                              void* d_out, int out_size, void* d_ws, size_t ws_size,
                              hipStream_t stream) {
    const float* Sf    = (const float*)d_in[0];
    const int*   edges = (const int*)d_in[1];
    const float* W     = (const float*)d_in[2];
    float* out = (float*)d_out;

    const int E = in_sizes[1] / 3;
    const int N = in_sizes[0] / HID;
    const int* etype = edges;
    const int* src   = edges + E;
    const int* tgt   = edges + 2 * E;
    int* ws = (int*)d_ws;

    const int CAP = E / 5 + 4096;   // per-type region capacity (>100 sigma margin)

    // mode2 layout
    int* ncnt = ws + 32;               // [N]
    int* noff = ncnt + N;              // [N+1]
    int* bsum = noff + N + 1;          // [256]
    size_t intsEnd = (size_t)(32 + N + (N + 1) + 256) * sizeof(int);
    size_t st2Off  = (intsEnd + 255) & ~(size_t)255;
    size_t wtOff   = ((st2Off + (size_t)NTYPES * CAP * sizeof(int2)) + 255) & ~(size_t)255;
    size_t sbOff   = ((wtOff + (size_t)NTYPES * HID * 256 * 2) + 255) & ~(size_t)255;
    size_t msgsOff = ((sbOff + (size_t)N * HID * 2) + 255) & ~(size_t)255;
    size_t need2   = msgsOff + (size_t)E * HID * 2;

    const int nb1 = (N + 1023) / 1024;
    const int eb  = (E + 255) / 256;
    const int nblocks = (E + E_TILE * TPB - 1) / (E_TILE * TPB) + 2 * NTYPES;
    ushort* Wt = (ushort*)((char*)d_ws + wtOff);
    int2* sortedT2 = (int2*)((char*)d_ws + st2Off);

    if (ws_size >= need2 && nb1 <= 256 && N < (1 << TNBITS)) {
        ushort* Sb   = (ushort*)((char*)d_ws + sbOff);
        ushort* msgs = (ushort*)((char*)d_ws + msgsOff);
        const int total = N * HID;
        const int n4 = (32 + N + 3) / 4;          // zero hdr + ncnt (overshoot ok)
        const int zb = (n4 + 255) / 256;
        const int sb = (total / 8 + 255) / 256;
        const int wb = (NTYPES * HID * 32 + 255) / 256;

        k_prep<<<zb + sb + wb, 256, 0, stream>>>((int4*)ws, n4, Sf, Sb, total, W, Wt, zb, sb);
        k_bin<1><<<eb, 256, 0, stream>>>(etype, src, tgt, E, CAP, ws, ncnt, sortedT2);
        k_scan1<<<nb1, 256, 0, stream>>>(ncnt, noff, bsum, N);
        k_scan2<<<1, 256, 0, stream>>>(bsum, nb1);
        k_gemm<2><<<nblocks, 256, 0, stream>>>(Sb, Sf, Wt, ws, sortedT2, CAP,
                                               noff, bsum, msgs, out);
        k_scatter<<<(N + 3) / 4, 256, 0, stream>>>(msgs, noff, bsum, out, N, E);
    } else {
        // fallback: type-bin + f32 gather + atomic scatter; ws: hdr | sortedT2 | Wt
        int2* sortedT0 = (int2*)((char*)d_ws + 256);
        ushort* Wt0 = (ushort*)((char*)d_ws + 256 +
                      (((size_t)NTYPES * CAP * sizeof(int2) + 255) & ~(size_t)255));

        k_prep<<<1 + (NTYPES * HID * 32 + 255) / 256, 256, 0, stream>>>(
            (int4*)ws, 8, nullptr, nullptr, 0, W, Wt0, 1, 0);
        hipMemsetAsync(d_out, 0, (size_t)out_size * sizeof(float), stream);
        k_bin<0><<<eb, 256, 0, stream>>>(etype, src, tgt, E, CAP, ws, nullptr, sortedT0);
        k_gemm<0><<<nblocks, 256, 0, stream>>>(nullptr, Sf, Wt0, ws, sortedT0, CAP,
                                               nullptr, nullptr, nullptr, out);
    }
}

// Round 14
// 152.707 us; speedup vs baseline: 1.0303x; 1.0303x over previous
//
#include <hip/hip_runtime.h>

#define NTYPES 6
#define HID 128
#define E_TILE 64
#define TPB 4
#define TNBITS 19
#define TNMASK ((1 << TNBITS) - 1)
#define DEG1F 0x40000000
#define OFFM  0x3FFFFFFF

typedef short short8 __attribute__((ext_vector_type(8)));
typedef float f32x4 __attribute__((ext_vector_type(4)));

static __device__ __forceinline__ ushort f2bf(float f) {
    union { float f; unsigned u; } v; v.f = f;
    unsigned r = v.u + 0x7FFFu + ((v.u >> 16) & 1u);   // RNE
    return (ushort)(r >> 16);
}

// ws ints: hdr[32] (hdr[30] = scan done-counter) | ncnt[N] | noff[N+1] | bsum[256]
// then 256B-aligned: sortedT2 int2[6*CAP] | Wt bf16[6][128][256] | Sb bf16[N][128] | msgs bf16[E][128]

// fused: zero(hdr+ncnt) || state f32->bf16 || W transpose/convert (block-range split)
__global__ void k_prep(int4* __restrict__ zp, int n4,
                       const float* __restrict__ Sf, ushort* __restrict__ Sb, int total,
                       const float* __restrict__ W, ushort* __restrict__ Wt,
                       int zb, int sb) {
    int b = blockIdx.x;
    if (b < zb) {
        int i = b * 256 + threadIdx.x;
        if (i < n4) zp[i] = make_int4(0, 0, 0, 0);
    } else if (b < zb + sb) {
        int g = ((b - zb) * 256 + threadIdx.x) * 8;
        if (g < total) {
            float4 a = *(const float4*)(Sf + g);
            float4 c = *(const float4*)(Sf + g + 4);
            ushort t[8] = { f2bf(a.x), f2bf(a.y), f2bf(a.z), f2bf(a.w),
                            f2bf(c.x), f2bf(c.y), f2bf(c.z), f2bf(c.w) };
            *(short8*)(Sb + g) = *(short8*)t;
        }
    } else {
        int t = (b - zb - sb) * 256 + threadIdx.x;
        int n  = t & 127;
        int k8 = (t >> 7) & 31;
        int ty = t >> 12;
        if (ty >= NTYPES) return;
        const float* wp = W + ((size_t)ty * 256 + (size_t)k8 * 8) * HID + n;
        ushort tmp[8];
        #pragma unroll
        for (int j = 0; j < 8; ++j) tmp[j] = f2bf(wp[(size_t)j * HID]);
        *(short8*)(Wt + ((size_t)ty * HID + n) * 256 + k8 * 8) = *(short8*)tmp;
    }
}

// single-pass type binning; packs {src, tgt | rank<<19} into per-type regions
template <int RANK>
__global__ void k_bin(const int* __restrict__ etype, const int* __restrict__ src,
                      const int* __restrict__ tgt, int E, int CAP,
                      int* __restrict__ hdr, int* __restrict__ ncnt,
                      int2* __restrict__ sortedT2) {
    __shared__ int lcnt[NTYPES];
    __shared__ int lbase[NTYPES];
    if (threadIdx.x < NTYPES) lcnt[threadIdx.x] = 0;
    __syncthreads();
    int i = blockIdx.x * 256 + threadIdx.x;
    bool valid = (i < E);
    int sn = 0, pk = 0, t = 0, lrk = 0;
    if (valid) {
        t  = etype[i] - 1;
        int tn = tgt[i];
        sn = src[i];
        int a = 0;
        if (RANK) a = atomicAdd(&ncnt[tn], 1);
        pk  = tn | (a << TNBITS);
        lrk = atomicAdd(&lcnt[t], 1);
    }
    __syncthreads();
    if (threadIdx.x < NTYPES) {
        int c = lcnt[threadIdx.x];
        lbase[threadIdx.x] = c ? atomicAdd(&hdr[16 + threadIdx.x], c) : 0;
    }
    __syncthreads();
    if (valid) {
        int pos = lbase[t] + lrk;
        if (pos < CAP) sortedT2[(size_t)t * CAP + pos] = make_int2(sn, pk);
    }
}

// fused scan: per-1024-chunk exclusive scan (deg-1 flag in bit 30) + last-block
// exclusive scan over bsum (done-counter pattern; hdr[30] zeroed by k_prep)
__global__ void k_scan(const int* __restrict__ ncnt, int* __restrict__ noff,
                       int* __restrict__ bsum, int* __restrict__ done, int N, int nb) {
    __shared__ int s[256];
    __shared__ int isLast;
    const int b = blockIdx.x, t = threadIdx.x;
    const int base = b * 1024 + t * 4;
    int v[4];
    #pragma unroll
    for (int i = 0; i < 4; ++i) v[i] = (base + i < N) ? ncnt[base + i] : 0;
    int tsum = v[0] + v[1] + v[2] + v[3];
    s[t] = tsum;
    __syncthreads();
    for (int off = 1; off < 256; off <<= 1) {
        int x = (t >= off) ? s[t - off] : 0;
        __syncthreads();
        s[t] += x;
        __syncthreads();
    }
    if (t == 255) bsum[b] = s[255];
    int run = s[t] - tsum;
    #pragma unroll
    for (int i = 0; i < 4; ++i)
        if (base + i < N) {
            noff[base + i] = run | ((v[i] == 1) ? DEG1F : 0);
            run += v[i];
        }

    // last block to finish scans bsum in place
    __threadfence();
    if (t == 0) isLast = (atomicAdd(done, 1) == gridDim.x - 1) ? 1 : 0;
    __syncthreads();
    if (!isLast) return;
    int bv = (t < nb) ? bsum[t] : 0;
    s[t] = bv;
    __syncthreads();
    for (int off = 1; off < 256; off <<= 1) {
        int x = (t >= off) ? s[t - off] : 0;
        __syncthreads();
        s[t] += x;
        __syncthreads();
    }
    if (t < nb) bsum[t] = s[t] - bv;   // exclusive
}

// ---------------- GEMM ----------------
// Block = TPB 64-edge tiles of ONE type. B fragments per-K-step from L2
// (compile-time offsets; no wreg array -> low VGPR). deg-1 (noff bit30) ->
// direct f32 out write. MODE 0: f32 gather + atomic scatter.
template <int MODE>
__launch_bounds__(256, 4)
__global__ void k_gemm(const ushort* __restrict__ Sb, const float* __restrict__ Sf,
                       const ushort* __restrict__ Wt, const int* __restrict__ hdr,
                       const int2* __restrict__ sortedT2, int CAP,
                       const int* __restrict__ noff, const int* __restrict__ bsum,
                       ushort* __restrict__ msgs, float* __restrict__ out) {
    __shared__ __align__(16) ushort Xs[E_TILE][264];   // 33792 B
    __shared__ int sN[TPB][E_TILE];
    __shared__ int tN[TPB][E_TILE];
    __shared__ int dstR[TPB][E_TILE];

    // map blockIdx -> (type, tile-group)
    int g = blockIdx.x;
    int ty, t0 = 0, ntl = 0, cnt_t = 0;
    for (ty = 0; ty < NTYPES; ++ty) {
        int c = hdr[16 + ty];
        if (c > CAP) c = CAP;
        int nt = (c + E_TILE - 1) >> 6;
        int ng = (nt + TPB - 1) / TPB;
        if (g < ng) {
            t0 = g * TPB;
            ntl = nt - t0; if (ntl > TPB) ntl = TPB;
            cnt_t = c;
            break;
        }
        g -= ng;
    }
    if (ty == NTYPES) return;

    const int tid = threadIdx.x;
    const int w  = tid >> 6;
    const int l  = tid & 63;
    const int lr = l & 15;
    const int lg = l >> 4;

    // index prefetch: wave tt covers tile tt (coalesced int2 loads)
    {
        const int tt = tid >> 6, s = l;
        if (tt < ntl) {
            int gp = (t0 + tt) * E_TILE + s;
            int sn = 0, tn = 0, dr = 0;
            if (gp < cnt_t) {
                int2 v = sortedT2[(size_t)ty * CAP + gp];
                sn = v.x;
                tn = v.y & TNMASK;
                if (MODE == 2) {
                    int a = ((unsigned)v.y) >> TNBITS;
                    int nf_ = noff[tn];
                    dr = (nf_ & DEG1F) ? -(tn + 1)
                                       : ((nf_ & OFFM) + bsum[tn >> 10] + a);
                }
            }
            sN[tt][s] = sn; tN[tt][s] = tn; dstR[tt][s] = dr;
        }
    }
    __syncthreads();

    // B-fragment base for this wave's 32 cols (L2-hot; offsets compile-time)
    const ushort* wb = Wt + ((size_t)ty * HID + w * 32 + lr) * 256 + 8 * lg;

    for (int tt = 0; tt < ntl; ++tt) {
        int cnt = cnt_t - (t0 + tt) * E_TILE;
        if (cnt > E_TILE) cnt = E_TILE;

        // ---- stage X = [state[src] | state[tgt]] bf16 [64][256]; 4 threads/edge ----
        {
            const int e = tid >> 2, q = tid & 3;   // thread covers 64 ushorts (128 B)
            ushort* dp = &Xs[e][q * 64];
            if (e < cnt) {
                const int node = (q & 2) ? tN[tt][e] : sN[tt][e];
                if (MODE == 2) {
                    const ushort* rp = Sb + (size_t)node * HID + (q & 1) * 64;
                    short8 v[8];
                    #pragma unroll
                    for (int i = 0; i < 8; ++i) v[i] = *(const short8*)(rp + i * 8);
                    #pragma unroll
                    for (int i = 0; i < 8; ++i) *(short8*)(dp + i * 8) = v[i];
                } else {
                    const float* rp = Sf + (size_t)node * HID + (q & 1) * 64;
                    #pragma unroll
                    for (int i = 0; i < 8; ++i) {
                        float4 a = *(const float4*)(rp + i * 8);
                        float4 b = *(const float4*)(rp + i * 8 + 4);
                        ushort tmp[8] = { f2bf(a.x), f2bf(a.y), f2bf(a.z), f2bf(a.w),
                                          f2bf(b.x), f2bf(b.y), f2bf(b.z), f2bf(b.w) };
                        *(short8*)(dp + i * 8) = *(short8*)tmp;
                    }
                }
            } else {
                short8 z = (short8){0, 0, 0, 0, 0, 0, 0, 0};
                #pragma unroll
                for (int i = 0; i < 8; ++i) *(short8*)(dp + i * 8) = z;
            }
        }
        __syncthreads();

        // ---- MFMA: wave w -> 64 edges x cols [w*32, w*32+32); B per-kk from L2 ----
        f32x4 acc[4][2];
        #pragma unroll
        for (int mf = 0; mf < 4; ++mf)
            #pragma unroll
            for (int nf = 0; nf < 2; ++nf)
                acc[mf][nf] = (f32x4){0.f, 0.f, 0.f, 0.f};

        const ushort* xb = &Xs[lr][8 * lg];
        #pragma unroll
        for (int kk = 0; kk < 8; ++kk) {
            const int k0 = kk * 32;
            short8 b0 = *(const short8*)(wb + k0);             // imm-offset folded
            short8 b1 = *(const short8*)(wb + 16 * 256 + k0);
            #pragma unroll
            for (int mf = 0; mf < 4; ++mf) {
                short8 a = *(const short8*)(xb + mf * 16 * 264 + k0);
                acc[mf][0] = __builtin_amdgcn_mfma_f32_16x16x32_bf16(a, b0, acc[mf][0], 0, 0, 0);
                acc[mf][1] = __builtin_amdgcn_mfma_f32_16x16x32_bf16(a, b1, acc[mf][1], 0, 0, 0);
            }
        }
        __syncthreads();   // Xs reads done before Os overlay

        float (*Os)[132] = (float (*)[132])&Xs[0][0];   // 64*132*4 = 33792 B exactly
        #pragma unroll
        for (int mf = 0; mf < 4; ++mf)
            #pragma unroll
            for (int nf = 0; nf < 2; ++nf)
                #pragma unroll
                for (int r = 0; r < 4; ++r)
                    Os[mf * 16 + lg * 4 + r][w * 32 + nf * 16 + lr] = acc[mf][nf][r];
        __syncthreads();

        if (MODE == 2) {
            const int r8e = tid >> 4, cg = tid & 15;
            #pragma unroll
            for (int rr = 0; rr < 4; ++rr) {
                int row = rr * 16 + r8e;
                if (row < cnt) {
                    int dr = dstR[tt][row];
                    float4 a = *(const float4*)&Os[row][cg * 8];
                    float4 b = *(const float4*)&Os[row][cg * 8 + 4];
                    if (dr >= 0) {
                        ushort tmp[8] = { f2bf(a.x), f2bf(a.y), f2bf(a.z), f2bf(a.w),
                                          f2bf(b.x), f2bf(b.y), f2bf(b.z), f2bf(b.w) };
                        *(short8*)(msgs + (size_t)dr * HID + cg * 8) = *(short8*)tmp;
                    } else {
                        float* op = out + (size_t)(-dr - 1) * HID + cg * 8;
                        *(float4*)op = a;
                        *(float4*)(op + 4) = b;
                    }
                }
            }
        } else {
            const int rA = tid >> 7;
            const int c  = tid & (HID - 1);
            for (int it = 0; it < E_TILE / 2; ++it) {
                int ee = it * 2 + rA;
                if (ee < cnt) atomicAdd(&out[(size_t)tN[tt][ee] * HID + c], Os[ee][c]);
            }
        }
        __syncthreads();   // Os reads done before next tile's staging
    }
}

// each 64-lane group owns one node; deg-1 rows (noff bit30) were written by gemm
__launch_bounds__(256)
__global__ void k_scatter(const ushort* __restrict__ msgs, const int* __restrict__ noff,
                          const int* __restrict__ bsum, float* __restrict__ out,
                          int N, int Etot) {
    int node = blockIdx.x * 4 + (threadIdx.x >> 6);
    if (node >= N) return;
    int raw = noff[node];
    if (raw & DEG1F) return;   // deg-1: gemm wrote f32 row directly
    int cp = threadIdx.x & 63;
    int s = (raw & OFFM) + bsum[node >> 10];
    int e = (node + 1 < N) ? ((noff[node + 1] & OFFM) + bsum[(node + 1) >> 10]) : Etot;
    float a0 = 0.f, a1 = 0.f;
    for (int r = s; r < e; ++r) {
        unsigned u = *(const unsigned*)(msgs + (size_t)r * HID + cp * 2);
        union { unsigned u; float f; } lo, hi;
        lo.u = u << 16; hi.u = u & 0xFFFF0000u;
        a0 += lo.f; a1 += hi.f;
    }
    *(float2*)(out + (size_t)node * HID + cp * 2) = make_float2(a0, a1);
}

extern "C" void kernel_launch(void* const* d_in, const int* in_sizes, int n_in,
                              void* d_out, int out_size, void* d_ws, size_t ws_size,
                              hipStream_t stream) {
    const float* Sf    = (const float*)d_in[0];
    const int*   edges = (const int*)d_in[1];
    const float* W     = (const float*)d_in[2];
    float* out = (float*)d_out;

    const int E = in_sizes[1] / 3;
    const int N = in_sizes[0] / HID;
    const int* etype = edges;
    const int* src   = edges + E;
    const int* tgt   = edges + 2 * E;
    int* ws = (int*)d_ws;

    const int CAP = E / 5 + 4096;   // per-type region capacity (>100 sigma margin)

    // mode2 layout
    int* ncnt = ws + 32;               // [N]
    int* noff = ncnt + N;              // [N+1]
    int* bsum = noff + N + 1;          // [256]
    size_t intsEnd = (size_t)(32 + N + (N + 1) + 256) * sizeof(int);
    size_t st2Off  = (intsEnd + 255) & ~(size_t)255;
    size_t wtOff   = ((st2Off + (size_t)NTYPES * CAP * sizeof(int2)) + 255) & ~(size_t)255;
    size_t sbOff   = ((wtOff + (size_t)NTYPES * HID * 256 * 2) + 255) & ~(size_t)255;
    size_t msgsOff = ((sbOff + (size_t)N * HID * 2) + 255) & ~(size_t)255;
    size_t need2   = msgsOff + (size_t)E * HID * 2;

    const int nb1 = (N + 1023) / 1024;
    const int eb  = (E + 255) / 256;
    const int nblocks = (E + E_TILE * TPB - 1) / (E_TILE * TPB) + 2 * NTYPES;
    ushort* Wt = (ushort*)((char*)d_ws + wtOff);
    int2* sortedT2 = (int2*)((char*)d_ws + st2Off);

    if (ws_size >= need2 && nb1 <= 256 && N < (1 << TNBITS)) {
        ushort* Sb   = (ushort*)((char*)d_ws + sbOff);
        ushort* msgs = (ushort*)((char*)d_ws + msgsOff);
        const int total = N * HID;
        const int n4 = (32 + N + 3) / 4;          // zero hdr + ncnt (overshoot ok)
        const int zb = (n4 + 255) / 256;
        const int sb = (total / 8 + 255) / 256;
        const int wb = (NTYPES * HID * 32 + 255) / 256;

        k_prep<<<zb + sb + wb, 256, 0, stream>>>((int4*)ws, n4, Sf, Sb, total, W, Wt, zb, sb);
        k_bin<1><<<eb, 256, 0, stream>>>(etype, src, tgt, E, CAP, ws, ncnt, sortedT2);
        k_scan<<<nb1, 256, 0, stream>>>(ncnt, noff, bsum, &ws[30], N, nb1);
        k_gemm<2><<<nblocks, 256, 0, stream>>>(Sb, Sf, Wt, ws, sortedT2, CAP,
                                               noff, bsum, msgs, out);
        k_scatter<<<(N + 3) / 4, 256, 0, stream>>>(msgs, noff, bsum, out, N, E);
    } else {
        // fallback: type-bin + f32 gather + atomic scatter; ws: hdr | sortedT2 | Wt
        int2* sortedT0 = (int2*)((char*)d_ws + 256);
        ushort* Wt0 = (ushort*)((char*)d_ws + 256 +
                      (((size_t)NTYPES * CAP * sizeof(int2) + 255) & ~(size_t)255));

        k_prep<<<1 + (NTYPES * HID * 32 + 255) / 256, 256, 0, stream>>>(
            (int4*)ws, 8, nullptr, nullptr, 0, W, Wt0, 1, 0);
        hipMemsetAsync(d_out, 0, (size_t)out_size * sizeof(float), stream);
        k_bin<0><<<eb, 256, 0, stream>>>(etype, src, tgt, E, CAP, ws, nullptr, sortedT0);
        k_gemm<0><<<nblocks, 256, 0, stream>>>(nullptr, Sf, Wt0, ws, sortedT0, CAP,
                                               nullptr, nullptr, nullptr, out);
    }
}

// Round 15
// 131.960 us; speedup vs baseline: 1.1923x; 1.1572x over previous
//
#include <hip/hip_runtime.h>

#define NTYPES 6
#define HID 128
#define E_TILE 64
#define TPB 4
#define TNBITS 19
#define TNMASK ((1 << TNBITS) - 1)

typedef short short8 __attribute__((ext_vector_type(8)));
typedef float f32x4 __attribute__((ext_vector_type(4)));

static __device__ __forceinline__ ushort f2bf(float f) {
    union { float f; unsigned u; } v; v.f = f;
    unsigned r = v.u + 0x7FFFu + ((v.u >> 16) & 1u);   // RNE
    return (ushort)(r >> 16);
}

// ws ints: hdr[32] | ncnt[N] | noff[N+1] | bsum[256]
// then 256B-aligned: sortedT2 int2[6*CAP] | Wt bf16[6][128][256] | Sb bf16[N][128] | msgs bf16[E][128]

// fused: zero(hdr+ncnt) || state f32->bf16 || W transpose/convert (block-range split)
__global__ void k_prep(int4* __restrict__ zp, int n4,
                       const float* __restrict__ Sf, ushort* __restrict__ Sb, int total,
                       const float* __restrict__ W, ushort* __restrict__ Wt,
                       int zb, int sb) {
    int b = blockIdx.x;
    if (b < zb) {
        int i = b * 256 + threadIdx.x;
        if (i < n4) zp[i] = make_int4(0, 0, 0, 0);
    } else if (b < zb + sb) {
        int g = ((b - zb) * 256 + threadIdx.x) * 8;
        if (g < total) {
            float4 a = *(const float4*)(Sf + g);
            float4 c = *(const float4*)(Sf + g + 4);
            ushort t[8] = { f2bf(a.x), f2bf(a.y), f2bf(a.z), f2bf(a.w),
                            f2bf(c.x), f2bf(c.y), f2bf(c.z), f2bf(c.w) };
            *(short8*)(Sb + g) = *(short8*)t;
        }
    } else {
        int t = (b - zb - sb) * 256 + threadIdx.x;
        int n  = t & 127;
        int k8 = (t >> 7) & 31;
        int ty = t >> 12;
        if (ty >= NTYPES) return;
        const float* wp = W + ((size_t)ty * 256 + (size_t)k8 * 8) * HID + n;
        ushort tmp[8];
        #pragma unroll
        for (int j = 0; j < 8; ++j) tmp[j] = f2bf(wp[(size_t)j * HID]);
        *(short8*)(Wt + ((size_t)ty * HID + n) * 256 + k8 * 8) = *(short8*)tmp;
    }
}

// single-pass type binning; packs {src, tgt | rank<<19} into per-type regions
template <int RANK>
__global__ void k_bin(const int* __restrict__ etype, const int* __restrict__ src,
                      const int* __restrict__ tgt, int E, int CAP,
                      int* __restrict__ hdr, int* __restrict__ ncnt,
                      int2* __restrict__ sortedT2) {
    __shared__ int lcnt[NTYPES];
    __shared__ int lbase[NTYPES];
    if (threadIdx.x < NTYPES) lcnt[threadIdx.x] = 0;
    __syncthreads();
    int i = blockIdx.x * 256 + threadIdx.x;
    bool valid = (i < E);
    int sn = 0, pk = 0, t = 0, lrk = 0;
    if (valid) {
        t  = etype[i] - 1;
        int tn = tgt[i];
        sn = src[i];
        int a = 0;
        if (RANK) a = atomicAdd(&ncnt[tn], 1);
        pk  = tn | (a << TNBITS);
        lrk = atomicAdd(&lcnt[t], 1);
    }
    __syncthreads();
    if (threadIdx.x < NTYPES) {
        int c = lcnt[threadIdx.x];
        lbase[threadIdx.x] = c ? atomicAdd(&hdr[16 + threadIdx.x], c) : 0;
    }
    __syncthreads();
    if (valid) {
        int pos = lbase[t] + lrk;
        if (pos < CAP) sortedT2[(size_t)t * CAP + pos] = make_int2(sn, pk);
    }
}

// per-1024-chunk exclusive scan; bsum[b] = chunk total
__global__ void k_scan1(const int* __restrict__ ncnt, int* __restrict__ noff,
                        int* __restrict__ bsum, int N) {
    __shared__ int s[256];
    const int b = blockIdx.x, t = threadIdx.x;
    const int base = b * 1024 + t * 4;
    int v[4];
    #pragma unroll
    for (int i = 0; i < 4; ++i) v[i] = (base + i < N) ? ncnt[base + i] : 0;
    int tsum = v[0] + v[1] + v[2] + v[3];
    s[t] = tsum;
    __syncthreads();
    for (int off = 1; off < 256; off <<= 1) {
        int x = (t >= off) ? s[t - off] : 0;
        __syncthreads();
        s[t] += x;
        __syncthreads();
    }
    if (t == 255) bsum[b] = s[255];
    int run = s[t] - tsum;
    #pragma unroll
    for (int i = 0; i < 4; ++i)
        if (base + i < N) { noff[base + i] = run; run += v[i]; }
}

__global__ void k_scan2(int* __restrict__ bsum, int nb) {
    __shared__ int s[256];
    const int t = threadIdx.x;
    int v = (t < nb) ? bsum[t] : 0;
    s[t] = v;
    __syncthreads();
    for (int off = 1; off < 256; off <<= 1) {
        int x = (t >= off) ? s[t - off] : 0;
        __syncthreads();
        s[t] += x;
        __syncthreads();
    }
    if (t < nb) bsum[t] = s[t] - v;   // exclusive
}

// ---------------- GEMM ----------------
// Block = TPB 64-edge tiles of ONE type. B fragments loaded per-K-step from L2
// (compile-time offsets; frees ~64 VGPRs -> 4 blocks/CU co-resident for the
// latency-bound gather). MODE 2: bf16 gather; deg-1 -> direct f32 out, else
// bf16 msgs. MODE 0: f32 gather + atomic scatter.
template <int MODE>
__launch_bounds__(256, 4)
__global__ void k_gemm(const ushort* __restrict__ Sb, const float* __restrict__ Sf,
                       const ushort* __restrict__ Wt, const int* __restrict__ hdr,
                       const int2* __restrict__ sortedT2, int CAP,
                       const int* __restrict__ ncnt, const int* __restrict__ noff,
                       const int* __restrict__ bsum,
                       ushort* __restrict__ msgs, float* __restrict__ out) {
    __shared__ __align__(16) ushort Xs[E_TILE][264];   // 33792 B
    __shared__ int sN[TPB][E_TILE];
    __shared__ int tN[TPB][E_TILE];
    __shared__ int dstR[TPB][E_TILE];

    // map blockIdx -> (type, tile-group)
    int g = blockIdx.x;
    int ty, t0 = 0, ntl = 0, cnt_t = 0;
    for (ty = 0; ty < NTYPES; ++ty) {
        int c = hdr[16 + ty];
        if (c > CAP) c = CAP;
        int nt = (c + E_TILE - 1) >> 6;
        int ng = (nt + TPB - 1) / TPB;
        if (g < ng) {
            t0 = g * TPB;
            ntl = nt - t0; if (ntl > TPB) ntl = TPB;
            cnt_t = c;
            break;
        }
        g -= ng;
    }
    if (ty == NTYPES) return;

    const int tid = threadIdx.x;
    const int w  = tid >> 6;
    const int l  = tid & 63;
    const int lr = l & 15;
    const int lg = l >> 4;

    // index prefetch: wave tt covers tile tt (coalesced int2 loads)
    {
        const int tt = tid >> 6, s = l;
        if (tt < ntl) {
            int gp = (t0 + tt) * E_TILE + s;
            int sn = 0, tn = 0, dr = 0;
            if (gp < cnt_t) {
                int2 v = sortedT2[(size_t)ty * CAP + gp];
                sn = v.x;
                tn = v.y & TNMASK;
                if (MODE == 2) {
                    int a = ((unsigned)v.y) >> TNBITS;
                    dr = (ncnt[tn] == 1) ? -(tn + 1)
                                         : (noff[tn] + bsum[tn >> 10] + a);
                }
            }
            sN[tt][s] = sn; tN[tt][s] = tn; dstR[tt][s] = dr;
        }
    }
    __syncthreads();

    // B-fragment base for this wave's 32 cols (L2-hot; offsets are compile-time)
    const ushort* wb = Wt + ((size_t)ty * HID + w * 32 + lr) * 256 + 8 * lg;

    for (int tt = 0; tt < ntl; ++tt) {
        int cnt = cnt_t - (t0 + tt) * E_TILE;
        if (cnt > E_TILE) cnt = E_TILE;

        // ---- stage X = [state[src] | state[tgt]] bf16 [64][256]; 4 threads/edge ----
        {
            const int e = tid >> 2, q = tid & 3;   // thread covers 64 ushorts (128 B)
            ushort* dp = &Xs[e][q * 64];
            if (e < cnt) {
                const int node = (q & 2) ? tN[tt][e] : sN[tt][e];
                if (MODE == 2) {
                    const ushort* rp = Sb + (size_t)node * HID + (q & 1) * 64;
                    short8 v[8];
                    #pragma unroll
                    for (int i = 0; i < 8; ++i) v[i] = *(const short8*)(rp + i * 8);
                    #pragma unroll
                    for (int i = 0; i < 8; ++i) *(short8*)(dp + i * 8) = v[i];
                } else {
                    const float* rp = Sf + (size_t)node * HID + (q & 1) * 64;
                    #pragma unroll
                    for (int i = 0; i < 8; ++i) {
                        float4 a = *(const float4*)(rp + i * 8);
                        float4 b = *(const float4*)(rp + i * 8 + 4);
                        ushort tmp[8] = { f2bf(a.x), f2bf(a.y), f2bf(a.z), f2bf(a.w),
                                          f2bf(b.x), f2bf(b.y), f2bf(b.z), f2bf(b.w) };
                        *(short8*)(dp + i * 8) = *(short8*)tmp;
                    }
                }
            } else {
                short8 z = (short8){0, 0, 0, 0, 0, 0, 0, 0};
                #pragma unroll
                for (int i = 0; i < 8; ++i) *(short8*)(dp + i * 8) = z;
            }
        }
        __syncthreads();

        // ---- MFMA: wave w -> 64 edges x cols [w*32, w*32+32); B per-kk from L2 ----
        f32x4 acc[4][2];
        #pragma unroll
        for (int mf = 0; mf < 4; ++mf)
            #pragma unroll
            for (int nf = 0; nf < 2; ++nf)
                acc[mf][nf] = (f32x4){0.f, 0.f, 0.f, 0.f};

        const ushort* xb = &Xs[lr][8 * lg];
        #pragma unroll
        for (int kk = 0; kk < 8; ++kk) {
            const int k0 = kk * 32;
            short8 b0 = *(const short8*)(wb + k0);             // imm-offset folded
            short8 b1 = *(const short8*)(wb + 16 * 256 + k0);
            #pragma unroll
            for (int mf = 0; mf < 4; ++mf) {
                short8 a = *(const short8*)(xb + mf * 16 * 264 + k0);
                acc[mf][0] = __builtin_amdgcn_mfma_f32_16x16x32_bf16(a, b0, acc[mf][0], 0, 0, 0);
                acc[mf][1] = __builtin_amdgcn_mfma_f32_16x16x32_bf16(a, b1, acc[mf][1], 0, 0, 0);
            }
        }
        __syncthreads();   // Xs reads done before Os overlay

        float (*Os)[132] = (float (*)[132])&Xs[0][0];   // 64*132*4 = 33792 B exactly
        #pragma unroll
        for (int mf = 0; mf < 4; ++mf)
            #pragma unroll
            for (int nf = 0; nf < 2; ++nf)
                #pragma unroll
                for (int r = 0; r < 4; ++r)
                    Os[mf * 16 + lg * 4 + r][w * 32 + nf * 16 + lr] = acc[mf][nf][r];
        __syncthreads();

        if (MODE == 2) {
            const int r8e = tid >> 4, cg = tid & 15;
            #pragma unroll
            for (int rr = 0; rr < 4; ++rr) {
                int row = rr * 16 + r8e;
                if (row < cnt) {
                    int dr = dstR[tt][row];
                    float4 a = *(const float4*)&Os[row][cg * 8];
                    float4 b = *(const float4*)&Os[row][cg * 8 + 4];
                    if (dr >= 0) {
                        ushort tmp[8] = { f2bf(a.x), f2bf(a.y), f2bf(a.z), f2bf(a.w),
                                          f2bf(b.x), f2bf(b.y), f2bf(b.z), f2bf(b.w) };
                        *(short8*)(msgs + (size_t)dr * HID + cg * 8) = *(short8*)tmp;
                    } else {
                        float* op = out + (size_t)(-dr - 1) * HID + cg * 8;
                        *(float4*)op = a;
                        *(float4*)(op + 4) = b;
                    }
                }
            }
        } else {
            const int rA = tid >> 7;
            const int c  = tid & (HID - 1);
            for (int it = 0; it < E_TILE / 2; ++it) {
                int ee = it * 2 + rA;
                if (ee < cnt) atomicAdd(&out[(size_t)tN[tt][ee] * HID + c], Os[ee][c]);
            }
        }
        __syncthreads();   // Os reads done before next tile's staging
    }
}

// each 64-lane group owns one node; deg-1 rows were written by gemm -> skip
__launch_bounds__(256)
__global__ void k_scatter(const ushort* __restrict__ msgs, const int* __restrict__ noff,
                          const int* __restrict__ bsum, float* __restrict__ out,
                          int N, int Etot) {
    int node = blockIdx.x * 4 + (threadIdx.x >> 6);
    if (node >= N) return;
    int cp = threadIdx.x & 63;
    int s = noff[node] + bsum[node >> 10];
    int e = (node + 1 < N) ? (noff[node + 1] + bsum[(node + 1) >> 10]) : Etot;
    if (e - s == 1) return;   // deg-1: gemm wrote f32 row directly
    float a0 = 0.f, a1 = 0.f;
    for (int r = s; r < e; ++r) {
        unsigned u = *(const unsigned*)(msgs + (size_t)r * HID + cp * 2);
        union { unsigned u; float f; } lo, hi;
        lo.u = u << 16; hi.u = u & 0xFFFF0000u;
        a0 += lo.f; a1 += hi.f;
    }
    *(float2*)(out + (size_t)node * HID + cp * 2) = make_float2(a0, a1);
}

extern "C" void kernel_launch(void* const* d_in, const int* in_sizes, int n_in,
                              void* d_out, int out_size, void* d_ws, size_t ws_size,
                              hipStream_t stream) {
    const float* Sf    = (const float*)d_in[0];
    const int*   edges = (const int*)d_in[1];
    const float* W     = (const float*)d_in[2];
    float* out = (float*)d_out;

    const int E = in_sizes[1] / 3;
    const int N = in_sizes[0] / HID;
    const int* etype = edges;
    const int* src   = edges + E;
    const int* tgt   = edges + 2 * E;
    int* ws = (int*)d_ws;

    const int CAP = E / 5 + 4096;   // per-type region capacity (>100 sigma margin)

    // mode2 layout
    int* ncnt = ws + 32;               // [N]
    int* noff = ncnt + N;              // [N+1]
    int* bsum = noff + N + 1;          // [256]
    size_t intsEnd = (size_t)(32 + N + (N + 1) + 256) * sizeof(int);
    size_t st2Off  = (intsEnd + 255) & ~(size_t)255;
    size_t wtOff   = ((st2Off + (size_t)NTYPES * CAP * sizeof(int2)) + 255) & ~(size_t)255;
    size_t sbOff   = ((wtOff + (size_t)NTYPES * HID * 256 * 2) + 255) & ~(size_t)255;
    size_t msgsOff = ((sbOff + (size_t)N * HID * 2) + 255) & ~(size_t)255;
    size_t need2   = msgsOff + (size_t)E * HID * 2;

    const int nb1 = (N + 1023) / 1024;
    const int eb  = (E + 255) / 256;
    const int nblocks = (E + E_TILE * TPB - 1) / (E_TILE * TPB) + 2 * NTYPES;
    ushort* Wt = (ushort*)((char*)d_ws + wtOff);
    int2* sortedT2 = (int2*)((char*)d_ws + st2Off);

    if (ws_size >= need2 && nb1 <= 256 && N < (1 << TNBITS)) {
        ushort* Sb   = (ushort*)((char*)d_ws + sbOff);
        ushort* msgs = (ushort*)((char*)d_ws + msgsOff);
        const int total = N * HID;
        const int n4 = (32 + N + 3) / 4;          // zero hdr + ncnt (overshoot ok)
        const int zb = (n4 + 255) / 256;
        const int sb = (total / 8 + 255) / 256;
        const int wb = (NTYPES * HID * 32 + 255) / 256;

        k_prep<<<zb + sb + wb, 256, 0, stream>>>((int4*)ws, n4, Sf, Sb, total, W, Wt, zb, sb);
        k_bin<1><<<eb, 256, 0, stream>>>(etype, src, tgt, E, CAP, ws, ncnt, sortedT2);
        k_scan1<<<nb1, 256, 0, stream>>>(ncnt, noff, bsum, N);
        k_scan2<<<1, 256, 0, stream>>>(bsum, nb1);
        k_gemm<2><<<nblocks, 256, 0, stream>>>(Sb, Sf, Wt, ws, sortedT2, CAP,
                                               ncnt, noff, bsum, msgs, out);
        k_scatter<<<(N + 3) / 4, 256, 0, stream>>>(msgs, noff, bsum, out, N, E);
    } else {
        // fallback: type-bin + f32 gather + atomic scatter; ws: hdr | sortedT2 | Wt
        int2* sortedT0 = (int2*)((char*)d_ws + 256);
        ushort* Wt0 = (ushort*)((char*)d_ws + 256 +
                      (((size_t)NTYPES * CAP * sizeof(int2) + 255) & ~(size_t)255));

        k_prep<<<1 + (NTYPES * HID * 32 + 255) / 256, 256, 0, stream>>>(
            (int4*)ws, 8, nullptr, nullptr, 0, W, Wt0, 1, 0);
        hipMemsetAsync(d_out, 0, (size_t)out_size * sizeof(float), stream);
        k_bin<0><<<eb, 256, 0, stream>>>(etype, src, tgt, E, CAP, ws, nullptr, sortedT0);
        k_gemm<0><<<nblocks, 256, 0, stream>>>(nullptr, Sf, Wt0, ws, sortedT0, CAP,
                                               nullptr, nullptr, nullptr, nullptr, out);
    }
}